// Round 1
// baseline (478.666 us; speedup 1.0000x reference)
//
#include <hip/hip_runtime.h>

// Problem constants (fixed by setup_inputs in the reference):
//   k,v: [B=2, C=128, Hc=48, Wc=48] fp32; NUM_HEADS=8 -> hd=16
//   WINDOW=5, DILATION=1 -> K=25 offsets, r=2
//   query grid 96x96, scale_factor=2
// Outputs (flat, concatenated):
//   out0 k_nb  [2,8,25,16,96,96]  = 58,982,400 floats
//   out1 v_nb  [2,8,25,16,96,96]  = 58,982,400 floats
//   out2 mask  [2,8,25,96,96]     =  3,686,400 floats (bool -> 0.0/1.0)

#define KV_ELEMS  58982400LL
#define MASK_OFF  117964800LL

// Each thread writes one float4 of k_nb and the matching float4 of v_nb.
// x4 = x/4; the 4 output x's {4x4..4x4+3} map to coarse x {2x4,2x4,2x4+1,2x4+1},
// so only 2 source loads per tensor per thread.
__global__ __launch_bounds__(256) void kv_expand_kernel(
    const float* __restrict__ k, const float* __restrict__ v,
    float* __restrict__ out_k, float* __restrict__ out_v) {
    int tid = blockIdx.x * blockDim.x + threadIdx.x;
    // decompose: tid = ((((b*8+h)*25+kk)*16+d)*96+y)*24 + x4
    int x4 = tid % 24;  int t = tid / 24;
    int y  = t % 96;    t /= 96;
    int d  = t % 16;    t /= 16;
    int kk = t % 25;    t /= 25;
    int h  = t % 8;
    int b  = t / 8;

    int dy = kk / 5 - 2;
    int dx = kk % 5 - 2;
    int yy = (y >> 1) + dy;                 // coarse row + offset
    bool vy = (unsigned)yy < 48u;
    int xc0 = 2 * x4 + dx;                  // coarse col for out x = 4*x4, 4*x4+1
    int xc1 = xc0 + 1;                      // coarse col for out x = 4*x4+2, 4*x4+3
    bool v0 = vy && ((unsigned)xc0 < 48u);
    bool v1 = vy && ((unsigned)xc1 < 48u);

    int base = ((b * 128 + h * 16 + d) * 48 + (vy ? yy : 0)) * 48;
    float k0 = v0 ? k[base + xc0] : 0.0f;
    float k1 = v1 ? k[base + xc1] : 0.0f;
    float w0 = v0 ? v[base + xc0] : 0.0f;
    float w1 = v1 ? v[base + xc1] : 0.0f;

    float4 ok = make_float4(k0, k0, k1, k1);
    float4 ov = make_float4(w0, w0, w1, w1);
    reinterpret_cast<float4*>(out_k)[tid] = ok;
    reinterpret_cast<float4*>(out_v)[tid] = ov;
}

__global__ __launch_bounds__(256) void mask_kernel(float* __restrict__ out_m) {
    int tid = blockIdx.x * blockDim.x + threadIdx.x;
    // decompose: tid = (((b*8+h)*25+kk)*96+y)*24 + x4   (b,h don't matter)
    int x4 = tid % 24;  int t = tid / 24;
    int y  = t % 96;    t /= 96;
    int kk = t % 25;

    int dy = kk / 5 - 2;
    int dx = kk % 5 - 2;
    int yy = (y >> 1) + dy;
    bool vy = (unsigned)yy < 48u;
    int xc0 = 2 * x4 + dx;
    bool v0 = vy && ((unsigned)xc0 < 48u);
    bool v1 = vy && ((unsigned)(xc0 + 1) < 48u);

    float m0 = v0 ? 1.0f : 0.0f;
    float m1 = v1 ? 1.0f : 0.0f;
    reinterpret_cast<float4*>(out_m)[tid] = make_float4(m0, m0, m1, m1);
}

extern "C" void kernel_launch(void* const* d_in, const int* in_sizes, int n_in,
                              void* d_out, int out_size, void* d_ws, size_t ws_size,
                              hipStream_t stream) {
    const float* k = (const float*)d_in[0];
    const float* v = (const float*)d_in[1];
    float* out = (float*)d_out;
    float* out_k = out;
    float* out_v = out + KV_ELEMS;
    float* out_m = out + MASK_OFF;

    // k/v expand: 58,982,400 / 4 = 14,745,600 threads = 57,600 blocks x 256
    kv_expand_kernel<<<57600, 256, 0, stream>>>(k, v, out_k, out_v);
    // mask: 3,686,400 / 4 = 921,600 threads = 3,600 blocks x 256
    mask_kernel<<<3600, 256, 0, stream>>>(out_m);
}